// Round 1
// baseline (1804.313 us; speedup 1.0000x reference)
//
#include <hip/hip_runtime.h>
#include <hip/hip_fp16.h>

#define RES 256
#define MS 256
#define ST 512
#define NB 32
#define LUTLEN 262144
#define LUTW 8192   // LUTLEN/32
#define NOUT 32

typedef __attribute__((ext_vector_type(8))) _Float16 half8;
typedef __attribute__((ext_vector_type(4))) float f32x4;

// Pack lut (RES x LUTLEN int32 0/1) into bitmask words: lutp[n*LUTW + w] holds
// bits 32w..32w+31 of node n's LUT row. 268MB -> 8MB (fits L2/L3).
__global__ void pack_lut_kernel(const int* __restrict__ lut, unsigned int* __restrict__ lutp) {
    const long long total = (long long)RES * LUTLEN;  // 67,108,864 (multiple of 64)
    const int gtid = blockIdx.x * blockDim.x + threadIdx.x;
    const int wave = gtid >> 6;
    const int lane = threadIdx.x & 63;
    const int nwaves = (gridDim.x * blockDim.x) >> 6;
    for (long long base = (long long)wave * 64; base < total; base += (long long)nwaves * 64) {
        int v = lut[base + lane];
        unsigned long long bm = __ballot(v != 0);
        if (lane == 0) {
            unsigned int* p = &lutp[base >> 5];
            p[0] = (unsigned int)bm;
            p[1] = (unsigned int)(bm >> 32);
        }
    }
}

// Pack x (M,S,NB bits) time-major: xp[t*MS + m] = 32 input bits for (sample m, step t).
__global__ void pack_x_kernel(const int* __restrict__ x, unsigned int* __restrict__ xp) {
    const long long total = (long long)MS * ST * NB;  // 4,194,304
    const int gtid = blockIdx.x * blockDim.x + threadIdx.x;
    const int wave = gtid >> 6;
    const int lane = threadIdx.x & 63;
    const int nwaves = (gridDim.x * blockDim.x) >> 6;
    for (long long base = (long long)wave * 64; base < total; base += (long long)nwaves * 64) {
        int v = x[base + lane];
        unsigned long long bm = __ballot(v != 0);
        if (lane == 0) {
            const int m = (int)(base >> 14);          // / (ST*NB)
            const int t0 = ((int)base & 16383) >> 5;  // (base % 16384) / 32
            xp[t0 * MS + m] = (unsigned int)bm;
            xp[(t0 + 1) * MS + m] = (unsigned int)(bm >> 32);
        }
    }
}

// Main recurrence: 16 blocks x 512 threads. Block b owns samples [16b, 16b+16).
// Per step: state_idx = (res*primes) @ W^T via 16x16x32 f16 MFMA (exact: primes<2048
// exact in f16, sums < 2^24 exact in f32 accum), LUT bit gather straight from the
// C-fragment registers, new state written to the other vA buffer with the NEXT
// step's input scatter folded in (one __syncthreads per step).
template<bool LP, bool XP>
__global__ void reservoir_kernel(
    const int* __restrict__ xraw,
    const unsigned int* __restrict__ xp,
    const int* __restrict__ lutraw,
    const unsigned int* __restrict__ lutp,
    const int* __restrict__ init_res,
    const int* __restrict__ W,
    const int* __restrict__ primes,
    const int* __restrict__ input_nodes,
    const float* __restrict__ rw,
    const float* __restrict__ rb,
    float* __restrict__ out)
{
    // vA[buf][m][k]: (res[k]*primes[k]) as f16 per sample m. Row padded 256->264
    // halves (stride 528B = 132 words == 4 mod 32 banks) to spread ds_read_b128.
    __shared__ __align__(16) _Float16 vA[2][16][264];

    const int tid = threadIdx.x;
    const int lane = tid & 63;
    const int wid = tid >> 6;    // 0..7, each wave owns 2 node-tiles of 16
    const int g = lane >> 4;     // 0..3 (k-group / sample-group)
    const int r = lane & 15;     // A row (sample) & B col (node-within-tile)
    const int m0 = blockIdx.x * 16;

    const int n0 = (wid * 2) * 16 + r;
    const int n1 = (wid * 2 + 1) * 16 + r;

    const _Float16 p0 = (_Float16)(float)primes[n0];
    const _Float16 p1 = (_Float16)(float)primes[n1];

    // inverse input-node map for this lane's two nodes
    int j0 = -1, j1 = -1;
    for (int j = 0; j < NB; ++j) {
        int nn = input_nodes[j];
        if (nn == n0) j0 = j;
        if (nn == n1) j1 = j;
    }

    // B fragments (constant across steps): B[k][j] = W[tile_node j][k], 0/1 in f16.
    half8 B0[8], B1[8];
#pragma unroll
    for (int kc = 0; kc < 8; ++kc) {
        const int kb = kc * 32 + g * 8;
        half8 b0, b1;
#pragma unroll
        for (int e = 0; e < 8; ++e) {
            b0[e] = (W[n0 * RES + kb + e] != 0) ? (_Float16)1.0f : (_Float16)0.0f;
            b1[e] = (W[n1 * RES + kb + e] != 0) ? (_Float16)1.0f : (_Float16)0.0f;
        }
        B0[kc] = b0; B1[kc] = b1;
    }

    // init vA[0] = init_res with step-0 input scatter applied
#pragma unroll
    for (int q = 0; q < 4; ++q) {
        const int m = 4 * g + q;
        int b0, b1;
        if (j0 >= 0) {
            b0 = XP ? (int)((xp[m0 + m] >> j0) & 1u)
                    : (xraw[((m0 + m) * ST) * NB + j0] != 0);
        } else b0 = (init_res[n0] != 0);
        if (j1 >= 0) {
            b1 = XP ? (int)((xp[m0 + m] >> j1) & 1u)
                    : (xraw[((m0 + m) * ST) * NB + j1] != 0);
        } else b1 = (init_res[n1] != 0);
        vA[0][m][n0] = b0 ? p0 : (_Float16)0.0f;
        vA[0][m][n1] = b1 ? p1 : (_Float16)0.0f;
    }
    __syncthreads();

    int cur = 0;
#pragma unroll 1
    for (int t = 0; t < ST; ++t) {
        // A fragments: row r, k contiguous (8 halves = ds_read_b128)
        half8 A[8];
#pragma unroll
        for (int kc = 0; kc < 8; ++kc) {
            A[kc] = *(const half8*)&vA[cur][r][kc * 32 + g * 8];
        }
        f32x4 c0 = {0.f, 0.f, 0.f, 0.f};
        f32x4 c1 = {0.f, 0.f, 0.f, 0.f};
#pragma unroll
        for (int kc = 0; kc < 8; ++kc) {
            c0 = __builtin_amdgcn_mfma_f32_16x16x32_f16(A[kc], B0[kc], c0, 0, 0, 0);
            c1 = __builtin_amdgcn_mfma_f32_16x16x32_f16(A[kc], B1[kc], c1, 0, 0, 0);
        }

        // LUT gather: C frag reg q holds state_idx for (sample 4g+q, node n0/n1)
        int bits0[4], bits1[4];
#pragma unroll
        for (int q = 0; q < 4; ++q) {
            const unsigned int i0 = (unsigned int)c0[q];
            const unsigned int i1 = (unsigned int)c1[q];
            if (LP) {
                const unsigned int w0 = lutp[n0 * LUTW + (int)(i0 >> 5)];
                const unsigned int w1 = lutp[n1 * LUTW + (int)(i1 >> 5)];
                bits0[q] = (int)((w0 >> (i0 & 31u)) & 1u);
                bits1[q] = (int)((w1 >> (i1 & 31u)) & 1u);
            } else {
                bits0[q] = (lutraw[(size_t)n0 * LUTLEN + i0] != 0);
                bits1[q] = (lutraw[(size_t)n1 * LUTLEN + i1] != 0);
            }
        }

        const bool last = (t == ST - 1);
        unsigned int xwa[4] = {0u, 0u, 0u, 0u};
        if (XP) {
            if (!last && (j0 >= 0 || j1 >= 0)) {
                const uint4 xw = *(const uint4*)&xp[(t + 1) * MS + m0 + 4 * g];
                xwa[0] = xw.x; xwa[1] = xw.y; xwa[2] = xw.z; xwa[3] = xw.w;
            }
        }

        // write next state; fold in step t+1's input scatter (skip after last step)
        const int nxt = cur ^ 1;
#pragma unroll
        for (int q = 0; q < 4; ++q) {
            const int m = 4 * g + q;
            int b0 = bits0[q], b1 = bits1[q];
            if (!last) {
                if (j0 >= 0) b0 = XP ? (int)((xwa[q] >> j0) & 1u)
                                     : (xraw[((m0 + m) * ST + (t + 1)) * NB + j0] != 0);
                if (j1 >= 0) b1 = XP ? (int)((xwa[q] >> j1) & 1u)
                                     : (xraw[((m0 + m) * ST + (t + 1)) * NB + j1] != 0);
            }
            vA[nxt][m][n0] = b0 ? p0 : (_Float16)0.0f;
            vA[nxt][m][n1] = b1 ? p1 : (_Float16)0.0f;
        }
        __syncthreads();
        cur = nxt;
    }

    // readout: cur == 0 after 512 toggles; state bit = (vA != 0) since primes != 0
    {
        const int m = tid >> 5;
        const int o = tid & 31;
        float acc = rb[o];
        for (int n = 0; n < RES; ++n) {
            if (vA[cur][m][n] != (_Float16)0.0f) acc += rw[o * RES + n];
        }
        out[(m0 + m) * NOUT + o] = acc;
    }
}

extern "C" void kernel_launch(void* const* d_in, const int* in_sizes, int n_in,
                              void* d_out, int out_size, void* d_ws, size_t ws_size,
                              hipStream_t stream) {
    const int* x           = (const int*)d_in[0];
    const int* lut         = (const int*)d_in[1];
    const int* init_res    = (const int*)d_in[2];
    const int* W           = (const int*)d_in[3];
    const int* primes      = (const int*)d_in[4];
    const int* input_nodes = (const int*)d_in[5];
    const float* rw        = (const float*)d_in[6];
    const float* rb        = (const float*)d_in[7];
    float* out = (float*)d_out;

    const size_t lutp_bytes = (size_t)RES * LUTW * sizeof(unsigned int); // 8 MB
    const size_t xp_bytes   = (size_t)ST * MS * sizeof(unsigned int);    // 512 KB

    unsigned int* lutp = nullptr;
    unsigned int* xp = nullptr;
    bool use_lp = false, use_xp = false;
    unsigned char* ws = (unsigned char*)d_ws;
    if (ws_size >= lutp_bytes + xp_bytes) {
        lutp = (unsigned int*)ws;
        xp = (unsigned int*)(ws + lutp_bytes);
        use_lp = use_xp = true;
    } else if (ws_size >= xp_bytes) {
        xp = (unsigned int*)ws;
        use_xp = true;
    }

    if (use_lp) hipLaunchKernelGGL(pack_lut_kernel, dim3(256), dim3(256), 0, stream, lut, lutp);
    if (use_xp) hipLaunchKernelGGL(pack_x_kernel, dim3(64), dim3(256), 0, stream, x, xp);

    if (use_lp)
        hipLaunchKernelGGL((reservoir_kernel<true, true>), dim3(16), dim3(512), 0, stream,
                           x, xp, lut, lutp, init_res, W, primes, input_nodes, rw, rb, out);
    else if (use_xp)
        hipLaunchKernelGGL((reservoir_kernel<false, true>), dim3(16), dim3(512), 0, stream,
                           x, xp, lut, lutp, init_res, W, primes, input_nodes, rw, rb, out);
    else
        hipLaunchKernelGGL((reservoir_kernel<false, false>), dim3(16), dim3(512), 0, stream,
                           x, xp, lut, lutp, init_res, W, primes, input_nodes, rw, rb, out);
}